// Round 11
// baseline (125.725 us; speedup 1.0000x reference)
//
#include <hip/hip_runtime.h>
#include <hip/hip_fp16.h>

// Problem constants (from reference) — ALL TENSORS ARE FLOAT32.
#define B_    1024
#define N_    256
#define E_    2304      // == 9 * 256 exactly
#define EPT_  9         // edges per thread in CSR build
#define FIN_  6
#define VEC_  26
#define HSTR_ 40        // f16 LDS row stride (80 B, 16B-aligned)
#define BPB_  2         // batches per block

typedef _Float16 half8 __attribute__((ext_vector_type(8)));
typedef float    f32x4 __attribute__((ext_vector_type(4)));

// ---------------------------------------------------------------------------
// 512 blocks x 1024 threads. Thread (u=t&255 node slot, bh=(t>>8)&1 batch,
// eh=t>>9 channel-half). Round-9 structure (tripwire-green, 114.9us) with the
// L2/L3 gather + MFMA additionally split across CHANNEL halves: eh=0 owns
// output cols 0-15 (reads row float4s 0,1), eh=1 owns cols 16-31 (float4s
// 2,3). Channel c's accumulation chain (edge order, hfma2 sequence) is
// unchanged — outputs remain BITWISE IDENTICAL to rounds 3/9 (the green
// lineage). CSR (t<256), L1, mean, emb, head run verbatim round-9 code on
// t<512. One extra barrier per MFMA layer: two waves now share a slab's rows
// (read full rows / write disjoint col halves), so afrag reads must complete
// block-wide before writebacks. LDS 53KB -> 2 blocks/CU = up to 32 waves/CU.
// NOTE: byte-identical resubmission after an infra-signature failure
// ("container failed twice", same as round 1 which passed on retry).
// ---------------------------------------------------------------------------
__global__ __launch_bounds__(1024) void fused_kernel(
    const float* __restrict__ gf,    // [B,N,6]
    const float* __restrict__ vec,   // [B,26]
    const int* __restrict__ src, const int* __restrict__ dst,
    const float* __restrict__ W1, const float* __restrict__ b1,   // [6,32],[32]
    const float* __restrict__ W2, const float* __restrict__ b2,   // [32,32]
    const float* __restrict__ W3, const float* __restrict__ b3,
    const float* __restrict__ We, const float* __restrict__ be,   // [32,32]
    const float* __restrict__ Wpi, const float* __restrict__ bpi, // [58,512],[512]
    const float* __restrict__ Wvf, const float* __restrict__ bvf,
    float2* __restrict__ out)        // f32 pairs; pi @ [0,262144), vf @ +262144
{
    __shared__ __align__(16) __half hbuf[BPB_][N_ * HSTR_];  // 40,960 B
    __shared__ unsigned int packedE[E_];                     //  9,216 B
    __shared__ float part[BPB_][8 * 33];
    __shared__ float hgl[BPB_][32];
    __shared__ float combS[BPB_][64];
    __shared__ int   wsum[4];

    const int t  = threadIdx.x;
    const int u  = t & 255;          // node slot
    const int bh = (t >> 8) & 1;     // batch half
    const int eh = t >> 9;           // channel half (0: cols 0-15, 1: 16-31)
    const int b0 = blockIdx.x * BPB_;
    const int lane = t & 63, wv = t >> 6;   // wv 0..15

    // ---- CSR scratch overlaid on hbuf[0] (consumed before feature staging) ----
    int*   deg_o  = (int*)&hbuf[0][0];          // [256]
    int*   deg_i  = (int*)&hbuf[0][0] + 256;    // [256]
    int*   scanA  = (int*)&hbuf[0][0] + 512;    // [256]
    int*   cursor = (int*)&hbuf[0][0] + 768;    // [256]
    int*   perm   = (int*)&hbuf[0][0] + 1024;   // [256]
    float* inv_o  = (float*)&hbuf[0][0] + 1280; // [256]
    float* inv_i  = (float*)&hbuf[0][0] + 1536; // [256]
    int*   bcnt   = (int*)&hbuf[0][0] + 1792;   // [64]
    int*   boff   = (int*)&hbuf[0][0] + 1856;   // [64]

    // ==================== CSR build: t<256 only (round-3 verbatim) =========
    if (t < 256) {
        deg_o[t] = 0; deg_i[t] = 0;
        if (t < 64) bcnt[t] = 0;
    }
    __syncthreads();

    int sB[EPT_], dB[EPT_];
    if (t < 256) {
#pragma unroll
        for (int i = 0; i < EPT_; ++i) { int e = t + 256 * i; sB[i] = src[e]; dB[i] = dst[e]; }
#pragma unroll
        for (int i = 0; i < EPT_; ++i) { atomicAdd(&deg_o[sB[i]], 1); atomicAdd(&deg_i[dB[i]], 1); }
    }
    __syncthreads();

    int x = 0, dI = 0, bucket = 0;
    if (t < 256) {
        dI = deg_i[t];
        {
            int dO = deg_o[t];
            inv_o[t] = dO > 0 ? rsqrtf((float)dO) : 0.f;
            inv_i[t] = dI > 0 ? rsqrtf((float)dI) : 0.f;
        }
        x = dI;
#pragma unroll
        for (int d = 1; d < 64; d <<= 1) {
            int y = __shfl_up(x, d, 64);
            if (lane >= d) x += y;
        }
        if (lane == 63) wsum[wv] = x;
        bucket = dI > 63 ? 63 : dI;
        atomicAdd(&bcnt[bucket], 1);
    }
    __syncthreads();

    if (t < 256) {
        int prefix = 0;
#pragma unroll
        for (int w = 0; w < 3; ++w) if (w < wv) prefix += wsum[w];
        int incl = x + prefix;
        scanA[t]  = incl;
        cursor[t] = incl - dI;
    }
    if (t < 64) {
        int c = bcnt[t], xx = c;
#pragma unroll
        for (int d = 1; d < 64; d <<= 1) {
            int y = __shfl_up(xx, d, 64);
            if (lane >= d) xx += y;
        }
        boff[t] = xx - c;   // exclusive
    }
    __syncthreads();

    if (t < 256) {
        { int pos = atomicAdd(&boff[bucket], 1); perm[pos] = t; }
#pragma unroll
        for (int i = 0; i < EPT_; ++i) {
            int s = sB[i], dd = dB[i];
            int pos = atomicAdd(&cursor[dd], 1);
            float nrm = inv_o[s] * inv_i[dd];
            unsigned short hh = __half_as_ushort(__float2half(nrm));
            packedE[pos] = ((unsigned int)s << 16) | (unsigned int)hh;
        }
    }
    __syncthreads();

    // node assignment (all threads); then overlay is dead
    const int node = perm[u];
    const int end  = scanA[node];
    const int beg  = end - deg_i[node];
    __syncthreads();

    // ---- stage node features: 512 threads per batch (cols 6,7 zero-pad) ----
    {
        const float* g = gf + (size_t)(b0 + bh) * (N_ * FIN_);
        for (int i = u + 256 * eh; i < N_ * 8; i += 512) {
            int n = i >> 3, k = i & 7;
            hbuf[bh][n * HSTR_ + k] = __float2half((k < FIN_) ? g[n * FIN_ + k] : 0.f);
        }
    }
    __syncthreads();

    const __half2 z2 = __float2half2_rn(0.f);

    // ---- layer 1 (eh==0 verbatim round-9): gather + [6x32] GEMM + relu ----
    {
        float o[32];
        if (eh == 0) {
            __half2 a2[4] = {z2, z2, z2, z2};
            for (int e = beg; e < end; ++e) {
                unsigned int uu = packedE[e];
                __half2 w2 = __half2half2(__ushort_as_half((unsigned short)(uu & 0xffffu)));
                int ro = (uu >> 16) * HSTR_;
                union { float4 f4; __half2 h2[4]; } r;
                r.f4 = *(const float4*)&hbuf[bh][ro];
#pragma unroll
                for (int q = 0; q < 4; ++q) a2[q] = __hfma2(w2, r.h2[q], a2[q]);
            }
#pragma unroll
            for (int j = 0; j < 32; ++j) o[j] = b1[j];
#pragma unroll
            for (int k = 0; k < FIN_; ++k) {
                float ak = (k & 1) ? __high2float(a2[k >> 1]) : __low2float(a2[k >> 1]);
                const float* wr = &W1[k * 32];
#pragma unroll
                for (int j = 0; j < 32; ++j) o[j] += ak * wr[j];
            }
        }
        __syncthreads();
        if (eh == 0) {
            union { float4 f4; __half2 h2[4]; } w;
            float4* row = (float4*)&hbuf[bh][node * HSTR_];
#pragma unroll
            for (int q = 0; q < 4; ++q) {
#pragma unroll
                for (int r = 0; r < 4; ++r)
                    w.h2[r] = __floats2half2_rn(fmaxf(o[8*q + 2*r], 0.f), fmaxf(o[8*q + 2*r + 1], 0.f));
                row[q] = w.f4;
            }
        }
    }
    __syncthreads();

    // ---- layers 2 & 3: channel-split gather + MFMA 16x16x32 ----
    const int m16  = lane & 15;       // MFMA row/col-within-16
    const int q4   = lane >> 4;       // quad index 0..3
    const int wb   = (wv >> 2) & 1;   // wave's batch for MFMA
    const int wch  = wv >> 3;         // wave's col half for MFMA
    const int slab = (wv & 3) * 64;   // wave's 64-node slab

    for (int L = 0; L < 2; ++L) {
        const float* Wl = (L == 0) ? W2 : W3;
        const float* Bl = (L == 0) ? b2 : b3;

        // prefetch this wave's B fragment + bias (overlaps gather below)
        half8 bfrag;
        float bias_c;
        {
            int col = m16 + 16 * wch;
#pragma unroll
            for (int j = 0; j < 8; ++j)
                bfrag[j] = (_Float16)Wl[(q4 * 8 + j) * 32 + col];
            bias_c = Bl[col];
        }

        // gather: this thread's channel half (float4s 2*eh, 2*eh+1 of each row)
        __half2 acc2[8];
#pragma unroll
        for (int j = 0; j < 8; ++j) acc2[j] = z2;
        for (int e = beg; e < end; ++e) {
            unsigned int uu = packedE[e];
            __half2 w2 = __half2half2(__ushort_as_half((unsigned short)(uu & 0xffffu)));
            int ro = (uu >> 16) * HSTR_;
            const float4* hr = (const float4*)&hbuf[bh][ro];
            union { float4 f4; __half2 h2[4]; } ra, rb;
            ra.f4 = hr[2 * eh]; rb.f4 = hr[2 * eh + 1];
#pragma unroll
            for (int q = 0; q < 4; ++q) {
                acc2[q]     = __hfma2(w2, ra.h2[q], acc2[q]);
                acc2[4 + q] = __hfma2(w2, rb.h2[q], acc2[4 + q]);
            }
        }
        __syncthreads();                     // all gather reads of h done
        {
            // stage agg half-row into hbuf (h is dead now); disjoint 16B chunks
            union { float4 f4; __half2 h2[4]; } w;
            float4* row = (float4*)&hbuf[bh][node * HSTR_];
#pragma unroll
            for (int r = 0; r < 4; ++r) w.h2[r] = acc2[r];
            row[2 * eh] = w.f4;
#pragma unroll
            for (int r = 0; r < 4; ++r) w.h2[r] = acc2[4 + r];
            row[2 * eh + 1] = w.f4;
        }
        __syncthreads();                     // agg visible to all

        // MFMA: wave (wb, wch, slab); reads full rows, writes its col half
        {
            half8 afrag[4];
#pragma unroll
            for (int g = 0; g < 4; ++g) {
                union { float4 f4; half8 h8; } uf;
                uf.f4 = *(const float4*)&hbuf[wb][(slab + g * 16 + m16) * HSTR_ + q4 * 8];
                afrag[g] = uf.h8;
            }
            f32x4 D[4];
#pragma unroll
            for (int g = 0; g < 4; ++g) {
                f32x4 c = {bias_c, bias_c, bias_c, bias_c};
                D[g] = __builtin_amdgcn_mfma_f32_16x16x32_f16(afrag[g], bfrag, c, 0, 0, 0);
            }
            __syncthreads();   // afrag reads complete before col-half writebacks
#pragma unroll
            for (int g = 0; g < 4; ++g) {
#pragma unroll
                for (int r = 0; r < 4; ++r) {
                    float v = fmaxf(D[g][r], 0.f);
                    hbuf[wb][(slab + g * 16 + q4 * 4 + r) * HSTR_ + wch * 16 + m16] = __float2half(v);
                }
            }
        }
        __syncthreads();
    }

    // ---- mean over nodes -> hg[32] per batch (t<512, round-9 verbatim) ----
    if (t < 512) {
        int j = u & 31, g8 = u >> 5;
        float s = 0.f;
        for (int i = 0; i < 32; ++i)
            s += __half2float(hbuf[bh][(g8 * 32 + i) * HSTR_ + j]);
        part[bh][g8 * 33 + j] = s;
    }
    __syncthreads();
    if (t < 64) {
        int bb = t >> 5, j = t & 31;
        float sum = 0.f;
#pragma unroll
        for (int g8 = 0; g8 < 8; ++g8) sum += part[bb][g8 * 33 + j];
        hgl[bb][j] = sum * (1.0f / 256.0f);
    }
    if (t < BPB_ * VEC_) {                   // vec -> comb low 26, both batches
        int bb = t / VEC_, j = t - bb * VEC_;
        combS[bb][j] = vec[(b0 + bb) * VEC_ + j];
    }
    __syncthreads();

    // ---- emb (f32): comb[26..58) ----
    if (t < 64) {
        int bb = t >> 5, j = t & 31;
        float v = be[j];
#pragma unroll
        for (int k = 0; k < 32; ++k) v += hgl[bb][k] * We[k * 32 + j];
        combS[bb][VEC_ + j] = v;
    }
    __syncthreads();

    // ---- head (t<512, round-9 verbatim): half 0 -> pi, half 1 -> vf ----
    if (t < 512) {
        const int mh = t >> 8;               // 0: pi, 1: vf
        const float* Wm = (mh == 0) ? Wpi : Wvf;
        const float* bm = (mh == 0) ? bpi : bvf;
        const float2 bp = ((const float2*)bm)[u];
        float2 a0 = bp, a1 = bp;
        const float2* Wr = (const float2*)Wm;    // [58][256] float2
        for (int k = 0; k < VEC_ + 32; ++k) {
            float2 a = Wr[k * 256 + u];
            float c0 = combS[0][k];              // uniform addr -> LDS broadcast
            float c1 = combS[1][k];
            a0.x += c0 * a.x; a0.y += c0 * a.y;
            a1.x += c1 * a.x; a1.y += c1 * a.y;
        }
        int base = mh * 262144;
        out[base + b0 * 256 + u]       = make_float2(fmaxf(a0.x, 0.f), fmaxf(a0.y, 0.f));
        out[base + (b0 + 1) * 256 + u] = make_float2(fmaxf(a1.x, 0.f), fmaxf(a1.y, 0.f));
    }
}

extern "C" void kernel_launch(void* const* d_in, const int* in_sizes, int n_in,
                              void* d_out, int out_size, void* d_ws, size_t ws_size,
                              hipStream_t stream)
{
    // d_in order: 0 gf, 1 vec, 2 src, 3 dst, 4 W1, 5 b1, 6 W2, 7 b2, 8 W3, 9 b3,
    //             10 W_emb, 11 b_emb, 12 W_pi, 13 b_pi, 14 W_vf, 15 b_vf
    fused_kernel<<<B_ / BPB_, 1024, 0, stream>>>(
        (const float*)d_in[0], (const float*)d_in[1],
        (const int*)d_in[2], (const int*)d_in[3],
        (const float*)d_in[4], (const float*)d_in[5],
        (const float*)d_in[6], (const float*)d_in[7],
        (const float*)d_in[8], (const float*)d_in[9],
        (const float*)d_in[10], (const float*)d_in[11],
        (const float*)d_in[12], (const float*)d_in[13],
        (const float*)d_in[14], (const float*)d_in[15],
        (float2*)d_out);
}

// Round 12
// 113.141 us; speedup vs baseline: 1.1112x; 1.1112x over previous
//
#include <hip/hip_runtime.h>
#include <hip/hip_fp16.h>

// Problem constants (from reference) — ALL TENSORS ARE FLOAT32.
#define B_    1024
#define N_    256
#define E_    2304      // == 9 * 256 exactly
#define EPT_  9         // edges per thread in CSR build
#define FIN_  6
#define VEC_  26
#define HSTR_ 40        // f16 LDS row stride (80 B, 16B-aligned)
#define BPB_  2         // batches per block

typedef _Float16 half8 __attribute__((ext_vector_type(8)));
typedef float    f32x4 __attribute__((ext_vector_type(4)));

// ---------------------------------------------------------------------------
// FINAL: round-9 kernel, byte-identical (best green result: 114.87 us).
// 512 blocks x 512 threads. Thread (u = t&255, bh = t>>8): u = node slot,
// bh = batch half. Round-3 per-batch instruction sequences (tripwire-green
// lineage) with the two batches split across thread halves: serial phase
// lengths halved, 8 waves/block, 3 blocks/CU (LDS 53 KB).
// Round-11 lesson encoded here: do NOT scale waves/block past 8 — barrier
// drain cost + duplicated edge decode made the 1024-thread channel-split
// 11 us slower. Rounds 5-7 lesson: the (256,2)+quad-gather code shape
// tripwire-fails; keep per-batch arithmetic byte-identical to round 3.
// ---------------------------------------------------------------------------
__global__ __launch_bounds__(512) void fused_kernel(
    const float* __restrict__ gf,    // [B,N,6]
    const float* __restrict__ vec,   // [B,26]
    const int* __restrict__ src, const int* __restrict__ dst,
    const float* __restrict__ W1, const float* __restrict__ b1,   // [6,32],[32]
    const float* __restrict__ W2, const float* __restrict__ b2,   // [32,32]
    const float* __restrict__ W3, const float* __restrict__ b3,
    const float* __restrict__ We, const float* __restrict__ be,   // [32,32]
    const float* __restrict__ Wpi, const float* __restrict__ bpi, // [58,512],[512]
    const float* __restrict__ Wvf, const float* __restrict__ bvf,
    float2* __restrict__ out)        // f32 pairs; pi @ [0,262144), vf @ +262144
{
    __shared__ __align__(16) __half hbuf[BPB_][N_ * HSTR_];  // 40,960 B
    __shared__ unsigned int packedE[E_];                     //  9,216 B
    __shared__ float part[BPB_][8 * 33];
    __shared__ float hgl[BPB_][32];
    __shared__ float combS[BPB_][64];
    __shared__ int   wsum[4];

    const int t  = threadIdx.x;
    const int u  = t & 255;          // node slot
    const int bh = t >> 8;           // batch half (0 or 1)
    const int b0 = blockIdx.x * BPB_;
    const int lane = t & 63, wv = t >> 6;   // wv 0..7

    // ---- CSR scratch overlaid on hbuf[0] (consumed before feature staging) ----
    int*   deg_o  = (int*)&hbuf[0][0];          // [256]
    int*   deg_i  = (int*)&hbuf[0][0] + 256;    // [256]
    int*   scanA  = (int*)&hbuf[0][0] + 512;    // [256]
    int*   cursor = (int*)&hbuf[0][0] + 768;    // [256]
    int*   perm   = (int*)&hbuf[0][0] + 1024;   // [256]
    float* inv_o  = (float*)&hbuf[0][0] + 1280; // [256]
    float* inv_i  = (float*)&hbuf[0][0] + 1536; // [256]
    int*   bcnt   = (int*)&hbuf[0][0] + 1792;   // [64]
    int*   boff   = (int*)&hbuf[0][0] + 1856;   // [64]

    // ==================== CSR build: t<256 only (round-3 verbatim) =========
    // 1. zero counters
    if (t < 256) {
        deg_o[t] = 0; deg_i[t] = 0;
        if (t < 64) bcnt[t] = 0;
    }
    __syncthreads();

    // 2. load edges, count degrees
    int sB[EPT_], dB[EPT_];
    if (t < 256) {
#pragma unroll
        for (int i = 0; i < EPT_; ++i) { int e = t + 256 * i; sB[i] = src[e]; dB[i] = dst[e]; }
#pragma unroll
        for (int i = 0; i < EPT_; ++i) { atomicAdd(&deg_o[sB[i]], 1); atomicAdd(&deg_i[dB[i]], 1); }
    }
    __syncthreads();

    // 3. inv factors + wave-level scan of deg_i + bucket counts
    int x = 0, dI = 0, bucket = 0;
    if (t < 256) {
        dI = deg_i[t];
        {
            int dO = deg_o[t];
            inv_o[t] = dO > 0 ? rsqrtf((float)dO) : 0.f;
            inv_i[t] = dI > 0 ? rsqrtf((float)dI) : 0.f;
        }
        x = dI;
#pragma unroll
        for (int d = 1; d < 64; d <<= 1) {
            int y = __shfl_up(x, d, 64);
            if (lane >= d) x += y;
        }
        if (lane == 63) wsum[wv] = x;
        bucket = dI > 63 ? 63 : dI;
        atomicAdd(&bcnt[bucket], 1);
    }
    __syncthreads();

    // 4. combine wave sums; bucket-offset scan
    if (t < 256) {
        int prefix = 0;
#pragma unroll
        for (int w = 0; w < 3; ++w) if (w < wv) prefix += wsum[w];
        int incl = x + prefix;
        scanA[t]  = incl;
        cursor[t] = incl - dI;
    }
    if (t < 64) {
        int c = bcnt[t], xx = c;
#pragma unroll
        for (int d = 1; d < 64; d <<= 1) {
            int y = __shfl_up(xx, d, 64);
            if (lane >= d) xx += y;
        }
        boff[t] = xx - c;   // exclusive
    }
    __syncthreads();

    // 5. degree-sorted perm scatter + edge scatter (f16 norm pack)
    if (t < 256) {
        { int pos = atomicAdd(&boff[bucket], 1); perm[pos] = t; }
#pragma unroll
        for (int i = 0; i < EPT_; ++i) {
            int s = sB[i], dd = dB[i];
            int pos = atomicAdd(&cursor[dd], 1);
            float nrm = inv_o[s] * inv_i[dd];
            unsigned short hh = __half_as_ushort(__float2half(nrm));
            packedE[pos] = ((unsigned int)s << 16) | (unsigned int)hh;
        }
    }
    __syncthreads();

    // 6. node assignment into registers (ALL 512 threads); then overlay dead
    const int node = perm[u];
    const int end  = scanA[node];
    const int beg  = end - deg_i[node];
    __syncthreads();

    // ---- stage node features: half bh stages batch bh (cols 6,7 zero-pad) ----
    {
        const float* g = gf + (size_t)(b0 + bh) * (N_ * FIN_);
        for (int i = u; i < N_ * 8; i += 256) {
            int n = i >> 3, k = i & 7;
            hbuf[bh][n * HSTR_ + k] = __float2half((k < FIN_) ? g[n * FIN_ + k] : 0.f);
        }
    }
    __syncthreads();

    const __half2 z2 = __float2half2_rn(0.f);

    // ---- layer 1: f16 gather (own batch) + f32 [6x32] GEMM + relu ----
    {
        __half2 a2[4] = {z2, z2, z2, z2};
        for (int e = beg; e < end; ++e) {
            unsigned int uu = packedE[e];
            __half2 w2 = __half2half2(__ushort_as_half((unsigned short)(uu & 0xffffu)));
            int ro = (uu >> 16) * HSTR_;
            union { float4 f4; __half2 h2[4]; } r;
            r.f4 = *(const float4*)&hbuf[bh][ro];
#pragma unroll
            for (int q = 0; q < 4; ++q) a2[q] = __hfma2(w2, r.h2[q], a2[q]);
        }
        float o[32];
#pragma unroll
        for (int j = 0; j < 32; ++j) o[j] = b1[j];
#pragma unroll
        for (int k = 0; k < FIN_; ++k) {
            float ak = (k & 1) ? __high2float(a2[k >> 1]) : __low2float(a2[k >> 1]);
            const float* wr = &W1[k * 32];
#pragma unroll
            for (int j = 0; j < 32; ++j) o[j] += ak * wr[j];
        }
        __syncthreads();
        union { float4 f4; __half2 h2[4]; } w;
        float4* row = (float4*)&hbuf[bh][node * HSTR_];
#pragma unroll
        for (int q = 0; q < 4; ++q) {
#pragma unroll
            for (int r = 0; r < 4; ++r)
                w.h2[r] = __floats2half2_rn(fmaxf(o[8*q + 2*r], 0.f), fmaxf(o[8*q + 2*r + 1], 0.f));
            row[q] = w.f4;
        }
    }
    __syncthreads();

    // ---- layers 2 & 3: f16 gather (own batch) + MFMA 16x16x32 GEMM ----
    const int m16  = lane & 15;       // MFMA row/col-within-16
    const int q4   = lane >> 4;       // quad index 0..3
    const int slab = (wv & 3) * 64;   // wave's 64-node slab within its batch
    const int wb   = wv >> 2;         // which batch this wave MFMAs

    for (int L = 0; L < 2; ++L) {
        const float* Wl = (L == 0) ? W2 : W3;
        const float* Bl = (L == 0) ? b2 : b3;

        // prefetch B fragments + bias (batch-invariant; overlaps gather below)
        half8 bfrag[2];
        float bias_c[2];
#pragma unroll
        for (int cb = 0; cb < 2; ++cb) {
            int col = m16 + 16 * cb;
#pragma unroll
            for (int j = 0; j < 8; ++j)
                bfrag[cb][j] = (_Float16)Wl[(q4 * 8 + j) * 32 + col];
            bias_c[cb] = Bl[col];
        }

        // gather: acc = sum_e w * h[src], own batch only (round-3 order)
        __half2 acc2[16];
#pragma unroll
        for (int j = 0; j < 16; ++j) acc2[j] = z2;
        for (int e = beg; e < end; ++e) {
            unsigned int uu = packedE[e];
            __half2 w2 = __half2half2(__ushort_as_half((unsigned short)(uu & 0xffffu)));
            int ro = (uu >> 16) * HSTR_;
            const float4* hr = (const float4*)&hbuf[bh][ro];
            union { float4 f4; __half2 h2[4]; } r0, r1, r2, r3;
            r0.f4 = hr[0]; r1.f4 = hr[1]; r2.f4 = hr[2]; r3.f4 = hr[3];
#pragma unroll
            for (int q = 0; q < 4; ++q) {
                acc2[q]      = __hfma2(w2, r0.h2[q], acc2[q]);
                acc2[4 + q]  = __hfma2(w2, r1.h2[q], acc2[4 + q]);
                acc2[8 + q]  = __hfma2(w2, r2.h2[q], acc2[8 + q]);
                acc2[12 + q] = __hfma2(w2, r3.h2[q], acc2[12 + q]);
            }
        }
        __syncthreads();                     // all gather reads of h done
        {
            // stage agg row into hbuf (h is dead now)
            union { float4 f4; __half2 h2[4]; } w;
            float4* row = (float4*)&hbuf[bh][node * HSTR_];
#pragma unroll
            for (int q = 0; q < 4; ++q) {
#pragma unroll
                for (int r = 0; r < 4; ++r) w.h2[r] = acc2[4 * q + r];
                row[q] = w.f4;
            }
        }
        __syncthreads();                     // agg visible to all

        // MFMA: wave wv handles slab (wv&3)*64 of batch wv>>2
        {
            half8 afrag[4];
#pragma unroll
            for (int g = 0; g < 4; ++g) {
                union { float4 f4; half8 h8; } uf;
                uf.f4 = *(const float4*)&hbuf[wb][(slab + g * 16 + m16) * HSTR_ + q4 * 8];
                afrag[g] = uf.h8;
            }
            f32x4 D[4][2];
#pragma unroll
            for (int g = 0; g < 4; ++g) {
#pragma unroll
                for (int cb = 0; cb < 2; ++cb) {
                    f32x4 c = {bias_c[cb], bias_c[cb], bias_c[cb], bias_c[cb]};
                    D[g][cb] = __builtin_amdgcn_mfma_f32_16x16x32_f16(afrag[g], bfrag[cb], c, 0, 0, 0);
                }
            }
            // relu + writeback: D row = q4*4 + r, col = cb*16+m16
#pragma unroll
            for (int g = 0; g < 4; ++g) {
#pragma unroll
                for (int cb = 0; cb < 2; ++cb) {
#pragma unroll
                    for (int r = 0; r < 4; ++r) {
                        float v = fmaxf(D[g][cb][r], 0.f);
                        hbuf[wb][(slab + g * 16 + q4 * 4 + r) * HSTR_ + cb * 16 + m16] = __float2half(v);
                    }
                }
            }
        }
        __syncthreads();
    }

    // ---- mean over nodes -> hg[32] per batch (f32; round-3 order per batch) ----
    {
        int j = u & 31, g8 = u >> 5;
        float s = 0.f;
        for (int i = 0; i < 32; ++i)
            s += __half2float(hbuf[bh][(g8 * 32 + i) * HSTR_ + j]);
        part[bh][g8 * 33 + j] = s;
    }
    __syncthreads();
    if (t < 64) {
        int bb = t >> 5, j = t & 31;
        float sum = 0.f;
#pragma unroll
        for (int g8 = 0; g8 < 8; ++g8) sum += part[bb][g8 * 33 + j];
        hgl[bb][j] = sum * (1.0f / 256.0f);
    }
    if (t < BPB_ * VEC_) {                   // vec -> comb low 26, both batches
        int bb = t / VEC_, j = t - bb * VEC_;
        combS[bb][j] = vec[(b0 + bb) * VEC_ + j];
    }
    __syncthreads();

    // ---- emb (f32): comb[26..58) ----
    if (t < 64) {
        int bb = t >> 5, j = t & 31;
        float v = be[j];
#pragma unroll
        for (int k = 0; k < 32; ++k) v += hgl[bb][k] * We[k * 32 + j];
        combS[bb][VEC_ + j] = v;
    }
    __syncthreads();

    // ---- head: half 0 -> pi (both batches), half 1 -> vf (both batches) ----
    {
        const float* Wm = (bh == 0) ? Wpi : Wvf;
        const float* bm = (bh == 0) ? bpi : bvf;
        const float2 bp = ((const float2*)bm)[u];
        float2 a0 = bp, a1 = bp;
        const float2* Wr = (const float2*)Wm;    // [58][256] float2
        for (int k = 0; k < VEC_ + 32; ++k) {
            float2 a = Wr[k * 256 + u];
            float c0 = combS[0][k];              // uniform addr -> LDS broadcast
            float c1 = combS[1][k];
            a0.x += c0 * a.x; a0.y += c0 * a.y;
            a1.x += c1 * a.x; a1.y += c1 * a.y;
        }
        int base = bh * 262144;
        out[base + b0 * 256 + u]       = make_float2(fmaxf(a0.x, 0.f), fmaxf(a0.y, 0.f));
        out[base + (b0 + 1) * 256 + u] = make_float2(fmaxf(a1.x, 0.f), fmaxf(a1.y, 0.f));
    }
}

extern "C" void kernel_launch(void* const* d_in, const int* in_sizes, int n_in,
                              void* d_out, int out_size, void* d_ws, size_t ws_size,
                              hipStream_t stream)
{
    // d_in order: 0 gf, 1 vec, 2 src, 3 dst, 4 W1, 5 b1, 6 W2, 7 b2, 8 W3, 9 b3,
    //             10 W_emb, 11 b_emb, 12 W_pi, 13 b_pi, 14 W_vf, 15 b_vf
    fused_kernel<<<B_ / BPB_, 512, 0, stream>>>(
        (const float*)d_in[0], (const float*)d_in[1],
        (const int*)d_in[2], (const int*)d_in[3],
        (const float*)d_in[4], (const float*)d_in[5],
        (const float*)d_in[6], (const float*)d_in[7],
        (const float*)d_in[8], (const float*)d_in[9],
        (const float*)d_in[10], (const float*)d_in[11],
        (const float*)d_in[12], (const float*)d_in[13],
        (const float*)d_in[14], (const float*)d_in[15],
        (float2*)d_out);
}